// Round 10
// baseline (70.995 us; speedup 1.0000x reference)
//
#include <hip/hip_runtime.h>

#define NN 4194304
#define NB 16384

typedef _Float16 half4 __attribute__((ext_vector_type(4)));
typedef float floatx4 __attribute__((ext_vector_type(4)));
typedef unsigned int uint;

__device__ __forceinline__ uint pk_u32(float lo, float hi) {
  return __builtin_bit_cast(uint, __builtin_amdgcn_cvt_pkrtz(lo, hi));
}

// D-fragment (4 f32) -> B-fragment (4 f16) with ReLU, all in-register.
// Valid because D: col=lane&15,row=(lane>>4)*4+r  ==  B: col=lane&15,k=(lane>>4)*4+i.
__device__ __forceinline__ half4 relu_cvt(floatx4 d) {
  uint2 u;
  u.x = pk_u32(d[0], d[1]);
  u.y = pk_u32(d[2], d[3]);
  half4 h = __builtin_bit_cast(half4, u);
  return __builtin_elementwise_max(h, half4{0, 0, 0, 0});
}

// DPP butterfly wave64 sum; total lands in lane 63. 6 VALU adds, no LDS.
template <int CTRL>
__device__ __forceinline__ float dpp_add(float x) {
  int y = __builtin_amdgcn_update_dpp(0, __builtin_bit_cast(int, x), CTRL,
                                      0xf, 0xf, true);
  return x + __builtin_bit_cast(float, y);
}
__device__ __forceinline__ float wave_sum(float x) {
  x = dpp_add<0x111>(x);  // row_shr:1
  x = dpp_add<0x112>(x);  // row_shr:2
  x = dpp_add<0x114>(x);  // row_shr:4
  x = dpp_add<0x118>(x);  // row_shr:8  -> lane15/31/47/63 hold row sums
  x = dpp_add<0x142>(x);  // row_bcast:15 -> lane31 = rows0+1, lane63 = rows2+3
  x = dpp_add<0x143>(x);  // row_bcast:31 -> lane63 = total
  return x;
}

// Segmented reduce + atomics. Fast path: wave entirely in one segment
// (avg run length = 256 -> ~99% of waves) uses DPP butterfly + 1 atomic pair.
__device__ __forceinline__ void seg_atomic_add2(int b, float vx, float vy,
                                                float* __restrict__ out) {
  const int lane = threadIdx.x & 63;
  int b0 = __builtin_amdgcn_readfirstlane(b);
  if (__ballot(b == b0) == ~0ull) {  // wave-uniform branch
    float sx = wave_sum(vx);
    float sy = wave_sum(vy);
    if (lane == 63) {
      atomicAdd(&out[2 * b0], sx);
      atomicAdd(&out[2 * b0 + 1], sy);
    }
    return;
  }
  // Slow path: segmented inclusive scan (batch sorted).
  int bprev = __shfl_up(b, 1);
  bool head = (lane == 0) || (b != bprev);
  unsigned long long hb = __ballot(head);
  unsigned long long mask_le = hb << (63 - lane);
  int run_start = lane - __clzll(mask_le);
  float sx = vx, sy = vy;
#pragma unroll
  for (int off = 1; off < 64; off <<= 1) {
    float ox = __shfl_up(sx, off);
    float oy = __shfl_up(sy, off);
    if (lane - off >= run_start) { sx += ox; sy += oy; }
  }
  int bnext = __shfl_down(b, 1);
  bool tail = (lane == 63) || (b != bnext);
  if (tail) {
    atomicAdd(&out[2 * b], sx);
    atomicAdd(&out[2 * b + 1], sy);
  }
}

__global__ __launch_bounds__(256) void centroid_kernel(
    const float2* __restrict__ pos, const int* __restrict__ batch,
    float* __restrict__ csum) {
  int i = blockIdx.x * 256 + threadIdx.x;
  float2 p = pos[i];
  int b = batch[i];
  seg_atomic_add2(b, p.x, p.y, csum);
}

__global__ __launch_bounds__(256) void graphvec_kernel(
    const float* __restrict__ csum, const float2* __restrict__ poi_pos,
    float* __restrict__ udc) {
  int i = blockIdx.x * 256 + threadIdx.x;
  float2 pp = poi_pos[i];
  float dcx = csum[2 * i] - pp.x;
  float dcy = csum[2 * i + 1] - pp.y;
  float inv = rsqrtf(dcx * dcx + dcy * dcy);
  udc[2 * i] = dcx * inv;
  udc[2 * i + 1] = dcy * inv;
}

// Prepack weights into A-fragments of mfma_f32_16x16x16f16 (W as A: M=out,K=in):
// A[row=lane&15][k=(lane>>4)*4 + i], stored as uint2 (4 packed f16).
// 7 tiles: 0:L1(10x3, bias folded at k=3) 1:L2 rows0-15(16x10) 2:L2 rows16-19
//          3:L3 k0-15(10x16of20) 4:L3 k16-19(10x4) 5:L4(5x10) 6:L5(1x5)
// Bias sets (5 x 16 f32): 0:B2[0:16] 1:B2[16:20] 2:B3 3:B4 4:B5
__global__ void prepack_kernel(
    const float* __restrict__ W1, const float* __restrict__ W2,
    const float* __restrict__ W3, const float* __restrict__ W4,
    const float* __restrict__ W5, const float* __restrict__ B1,
    const float* __restrict__ B2, const float* __restrict__ B3,
    const float* __restrict__ B4, const float* __restrict__ B5,
    uint2* __restrict__ Wf, float* __restrict__ Bf) {
  int p = blockIdx.x * 256 + threadIdx.x;
  if (p < 448) {
    int tile = p >> 6, lane = p & 63, row = lane & 15, kb = (lane >> 4) * 4;
    const float* W;
    int outb = 0, outc, K, ld, koff = 0;
    switch (tile) {
      case 0: W = W1; outc = 10; K = 3;  ld = 3;  break;
      case 1: W = W2; outc = 16; K = 10; ld = 10; break;
      case 2: W = W2; outb = 16; outc = 4; K = 10; ld = 10; break;
      case 3: W = W3; outc = 10; K = 16; ld = 20; break;
      case 4: W = W3; outc = 10; K = 4;  ld = 20; koff = 16; break;
      case 5: W = W4; outc = 5;  K = 10; ld = 10; break;
      default: W = W5; outc = 1; K = 5;  ld = 5;  break;
    }
    float v[4];
#pragma unroll
    for (int i = 0; i < 4; ++i) {
      int k = kb + i;
      v[i] = (row < outc && k < K) ? W[(outb + row) * ld + koff + k] : 0.f;
      if (tile == 0 && row < outc && k == 3) v[i] = B1[row];  // bias fold
    }
    Wf[p] = uint2{pk_u32(v[0], v[1]), pk_u32(v[2], v[3])};
  } else if (p < 448 + 80) {
    int q = p - 448, set = q >> 4, n = q & 15;
    float v = 0.f;
    switch (set) {
      case 0: v = B2[n]; break;
      case 1: if (n < 4) v = B2[16 + n]; break;
      case 2: if (n < 10) v = B3[n]; break;
      case 3: if (n < 5) v = B4[n]; break;
      default: if (n < 1) v = B5[0]; break;
    }
    Bf[q] = v;
  }
}

__device__ __forceinline__ floatx4 mfma16(half4 a, half4 b, floatx4 c) {
  return __builtin_amdgcn_mfma_f32_16x16x16f16(a, b, c, 0, 0, 0);
}

__global__ __launch_bounds__(256, 4) void main_kernel(
    const float* __restrict__ t, const float2* __restrict__ pos,
    const float* __restrict__ poi_t, const float2* __restrict__ poi_pos,
    const int* __restrict__ batch, const float2* __restrict__ udc,
    const uint2* __restrict__ Wf, const float* __restrict__ Bf,
    float* __restrict__ out) {
  // NO LDS in this kernel: all lane permutations via shuffles (register
  // crossbar), so there is no memory ordering to get wrong.
  const int tid = threadIdx.x;
  const int lane = tid & 63;
  const int col = lane & 15;
  const int koct = lane >> 4;

  // Weight A-fragments (7 tiles x 4 f16) + bias C-fragments (5 x 4 f32).
  half4 wa[7];
#pragma unroll
  for (int k = 0; k < 7; ++k)
    wa[k] = __builtin_bit_cast(half4, Wf[k * 64 + lane]);
  floatx4 cb[5];
#pragma unroll
  for (int s = 0; s < 5; ++s)
    cb[s] = *(const floatx4*)&Bf[s * 16 + koct * 4];
  floatx4 cz{0.f, 0.f, 0.f, 0.f};

  // Per-node features (thread = node).
  int i = blockIdx.x * 256 + tid;
  int b = batch[i];
  float2 p = pos[i];
  float tv = t[i];
  float2 pp = poi_pos[b];
  float2 u = udc[b];
  float f0 = tv - poi_t[b];
  float dpx = p.x - pp.x, dpy = p.y - pp.y;
  float f1 = dpx * dpx + dpy * dpy;
  float inv_r = rsqrtf(f1);
  float f2 = (dpx * u.x + dpy * u.y) * inv_r;

  // feat = {f0, f1, f2, 1.0}: the 1.0 multiplies the folded L1 bias column.
  int fx = (int)pk_u32(f0, f1);
  int fy = (int)pk_u32(f2, 1.0f);

  // Gather B1 fragments: lane (col,koct) needs node g*16+col's features,
  // which live in lane g*16+col. Two 32-bit shuffles per group.
  half4 b1[4];
#pragma unroll
  for (int g = 0; g < 4; ++g) {
    int src = g * 16 + col;
    uint2 fr;
    fr.x = (uint)__shfl(fx, src);
    fr.y = (uint)__shfl(fy, src);
    b1[g] = __builtin_bit_cast(half4, fr);
  }

  // Layer-major schedule: 4 independent group-chains in flight at all times.
  floatx4 d[4];
  half4 a[4];
#pragma unroll
  for (int g = 0; g < 4; ++g) d[g] = mfma16(wa[0], b1[g], cz);   // L1
#pragma unroll
  for (int g = 0; g < 4; ++g) a[g] = relu_cvt(d[g]);

  floatx4 d2a[4], d2b[4];
#pragma unroll
  for (int g = 0; g < 4; ++g) d2a[g] = mfma16(wa[1], a[g], cb[0]);  // L2 M0-15
#pragma unroll
  for (int g = 0; g < 4; ++g) d2b[g] = mfma16(wa[2], a[g], cb[1]);  // L2 M16-19
  half4 a3a[4], a3b[4];
#pragma unroll
  for (int g = 0; g < 4; ++g) a3a[g] = relu_cvt(d2a[g]);
#pragma unroll
  for (int g = 0; g < 4; ++g) a3b[g] = relu_cvt(d2b[g]);

#pragma unroll
  for (int g = 0; g < 4; ++g) d[g] = mfma16(wa[3], a3a[g], cb[2]);  // L3 k0-15
#pragma unroll
  for (int g = 0; g < 4; ++g) d[g] = mfma16(wa[4], a3b[g], d[g]);   // L3 k16-19
#pragma unroll
  for (int g = 0; g < 4; ++g) a[g] = relu_cvt(d[g]);

#pragma unroll
  for (int g = 0; g < 4; ++g) d[g] = mfma16(wa[5], a[g], cb[3]);    // L4
#pragma unroll
  for (int g = 0; g < 4; ++g) a[g] = relu_cvt(d[g]);

#pragma unroll
  for (int g = 0; g < 4; ++g) d[g] = mfma16(wa[6], a[g], cb[4]);    // L5

  // w for node l = group l>>4, in-group col l&15: held by lane l&15 (koct=0)
  // in d[l>>4][0]. Broadcast each group's row-0 from lane col, then select
  // by koct with a static cndmask chain (no dynamic array indexing).
  float wg0 = __shfl(d[0][0], col);
  float wg1 = __shfl(d[1][0], col);
  float wg2 = __shfl(d[2][0], col);
  float wg3 = __shfl(d[3][0], col);
  float w = wg0;
  w = (koct == 1) ? wg1 : w;
  w = (koct == 2) ? wg2 : w;
  w = (koct == 3) ? wg3 : w;

  // F.normalize: unit = diff_pos * rsqrt(r2); reuse inv_r (guard f1==0 -> 0).
  float invn = (f1 > 0.f) ? inv_r : 0.f;
  seg_atomic_add2(b, w * dpx * invn, w * dpy * invn, out);
}

extern "C" void kernel_launch(void* const* d_in, const int* in_sizes, int n_in,
                              void* d_out, int out_size, void* d_ws,
                              size_t ws_size, hipStream_t stream) {
  const float* t = (const float*)d_in[0];
  const float2* pos = (const float2*)d_in[1];
  const float* poi_t = (const float*)d_in[2];
  const float2* poi_pos = (const float2*)d_in[3];
  const int* batch = (const int*)d_in[4];
  const float* W1 = (const float*)d_in[5];
  const float* B1 = (const float*)d_in[6];
  const float* W2 = (const float*)d_in[7];
  const float* B2 = (const float*)d_in[8];
  const float* W3 = (const float*)d_in[9];
  const float* B3 = (const float*)d_in[10];
  const float* W4 = (const float*)d_in[11];
  const float* B4 = (const float*)d_in[12];
  const float* W5 = (const float*)d_in[13];
  const float* B5 = (const float*)d_in[14];
  float* out = (float*)d_out;

  float* csum = (float*)d_ws;                  // [NB*2]
  float* udc = csum + 2 * NB;                  // [NB*2]
  uint2* Wf = (uint2*)(udc + 2 * NB);          // [448]
  float* Bf = (float*)(Wf + 448);              // [80]

  hipMemsetAsync(csum, 0, 2 * NB * sizeof(float), stream);
  hipMemsetAsync(d_out, 0, 2 * NB * sizeof(float), stream);

  prepack_kernel<<<3, 256, 0, stream>>>(W1, W2, W3, W4, W5, B1, B2, B3, B4,
                                        B5, Wf, Bf);
  centroid_kernel<<<NN / 256, 256, 0, stream>>>(pos, batch, csum);
  graphvec_kernel<<<NB / 256, 256, 0, stream>>>(csum, poi_pos, udc);
  main_kernel<<<NN / 256, 256, 0, stream>>>(
      t, pos, poi_t, poi_pos, batch, (const float2*)udc, Wf, Bf, out);
}

// Round 11
// 58.459 us; speedup vs baseline: 1.2144x; 1.2144x over previous
//
#include <hip/hip_runtime.h>

#define NN 4194304
#define NB 16384

typedef _Float16 half4 __attribute__((ext_vector_type(4)));
typedef float floatx4 __attribute__((ext_vector_type(4)));
typedef unsigned int uint;

__device__ __forceinline__ uint pk_u32(float lo, float hi) {
  return __builtin_bit_cast(uint, __builtin_amdgcn_cvt_pkrtz(lo, hi));
}

__device__ __forceinline__ half4 relu_cvt(floatx4 d) {
  uint2 u;
  u.x = pk_u32(d[0], d[1]);
  u.y = pk_u32(d[2], d[3]);
  half4 h = __builtin_bit_cast(half4, u);
  return __builtin_elementwise_max(h, half4{0, 0, 0, 0});
}

// DPP butterfly wave64 sum; total lands in lane 63. 6 VALU adds, no LDS.
template <int CTRL>
__device__ __forceinline__ float dpp_add(float x) {
  int y = __builtin_amdgcn_update_dpp(0, __builtin_bit_cast(int, x), CTRL,
                                      0xf, 0xf, true);
  return x + __builtin_bit_cast(float, y);
}
__device__ __forceinline__ float wave_sum(float x) {
  x = dpp_add<0x111>(x);
  x = dpp_add<0x112>(x);
  x = dpp_add<0x114>(x);
  x = dpp_add<0x118>(x);
  x = dpp_add<0x142>(x);
  x = dpp_add<0x143>(x);
  return x;
}

// Segmented reduce + atomics. Fast path: wave-uniform segment (avg run = 256).
__device__ __forceinline__ void seg_atomic_add2(int b, float vx, float vy,
                                                float* __restrict__ out) {
  const int lane = threadIdx.x & 63;
  int b0 = __builtin_amdgcn_readfirstlane(b);
  if (__ballot(b == b0) == ~0ull) {
    float sx = wave_sum(vx);
    float sy = wave_sum(vy);
    if (lane == 63) {
      atomicAdd(&out[2 * b0], sx);
      atomicAdd(&out[2 * b0 + 1], sy);
    }
    return;
  }
  int bprev = __shfl_up(b, 1);
  bool head = (lane == 0) || (b != bprev);
  unsigned long long hb = __ballot(head);
  unsigned long long mask_le = hb << (63 - lane);
  int run_start = lane - __clzll(mask_le);
  float sx = vx, sy = vy;
#pragma unroll
  for (int off = 1; off < 64; off <<= 1) {
    float ox = __shfl_up(sx, off);
    float oy = __shfl_up(sy, off);
    if (lane - off >= run_start) { sx += ox; sy += oy; }
  }
  int bnext = __shfl_down(b, 1);
  bool tail = (lane == 63) || (b != bnext);
  if (tail) {
    atomicAdd(&out[2 * b], sx);
    atomicAdd(&out[2 * b + 1], sy);
  }
}

// 4 nodes/thread: loads hoisted, stalls amortized.
__global__ __launch_bounds__(256) void centroid_kernel(
    const float2* __restrict__ pos, const int* __restrict__ batch,
    float* __restrict__ csum) {
  int base = blockIdx.x * 1024 + threadIdx.x;
  int bi[4];
  float2 pv[4];
#pragma unroll
  for (int r = 0; r < 4; ++r) {
    bi[r] = batch[base + r * 256];
    pv[r] = pos[base + r * 256];
  }
#pragma unroll
  for (int r = 0; r < 4; ++r) seg_atomic_add2(bi[r], pv[r].x, pv[r].y, csum);
}

// Per-graph packed record: {poi_pos.x, poi_pos.y, udc.x, udc.y}
__global__ __launch_bounds__(256) void graphvec_kernel(
    const float* __restrict__ csum, const float2* __restrict__ poi_pos,
    float4* __restrict__ pg) {
  int i = blockIdx.x * 256 + threadIdx.x;
  float2 pp = poi_pos[i];
  float dcx = csum[2 * i] - pp.x;
  float dcy = csum[2 * i + 1] - pp.y;
  float inv = rsqrtf(dcx * dcx + dcy * dcy);
  pg[i] = float4{pp.x, pp.y, dcx * inv, dcy * inv};
}

// Prepack weights into A-fragments of mfma_f32_16x16x16f16 (W as A: M=out,K=in):
// A[row=lane&15][k=(lane>>4)*4 + i], stored as uint2 (4 packed f16).
// 7 tiles: 0:L1(10x3, bias folded at k=3) 1:L2 rows0-15(16x10) 2:L2 rows16-19
//          3:L3 k0-15(10x16of20) 4:L3 k16-19(10x4) 5:L4(5x10) 6:L5(1x5)
// Bias sets (5 x 16 f32): 0:B2[0:16] 1:B2[16:20] 2:B3 3:B4 4:B5
__global__ void prepack_kernel(
    const float* __restrict__ W1, const float* __restrict__ W2,
    const float* __restrict__ W3, const float* __restrict__ W4,
    const float* __restrict__ W5, const float* __restrict__ B1,
    const float* __restrict__ B2, const float* __restrict__ B3,
    const float* __restrict__ B4, const float* __restrict__ B5,
    uint2* __restrict__ Wf, float* __restrict__ Bf) {
  int p = blockIdx.x * 256 + threadIdx.x;
  if (p < 448) {
    int tile = p >> 6, lane = p & 63, row = lane & 15, kb = (lane >> 4) * 4;
    const float* W;
    int outb = 0, outc, K, ld, koff = 0;
    switch (tile) {
      case 0: W = W1; outc = 10; K = 3;  ld = 3;  break;
      case 1: W = W2; outc = 16; K = 10; ld = 10; break;
      case 2: W = W2; outb = 16; outc = 4; K = 10; ld = 10; break;
      case 3: W = W3; outc = 10; K = 16; ld = 20; break;
      case 4: W = W3; outc = 10; K = 4;  ld = 20; koff = 16; break;
      case 5: W = W4; outc = 5;  K = 10; ld = 10; break;
      default: W = W5; outc = 1; K = 5;  ld = 5;  break;
    }
    float v[4];
#pragma unroll
    for (int i = 0; i < 4; ++i) {
      int k = kb + i;
      v[i] = (row < outc && k < K) ? W[(outb + row) * ld + koff + k] : 0.f;
      if (tile == 0 && row < outc && k == 3) v[i] = B1[row];  // bias fold
    }
    Wf[p] = uint2{pk_u32(v[0], v[1]), pk_u32(v[2], v[3])};
  } else if (p < 448 + 80) {
    int q = p - 448, set = q >> 4, n = q & 15;
    float v = 0.f;
    switch (set) {
      case 0: v = B2[n]; break;
      case 1: if (n < 4) v = B2[16 + n]; break;
      case 2: if (n < 10) v = B3[n]; break;
      case 3: if (n < 5) v = B4[n]; break;
      default: if (n < 1) v = B5[0]; break;
    }
    Bf[q] = v;
  }
}

__device__ __forceinline__ floatx4 mfma16(half4 a, half4 b, floatx4 c) {
  return __builtin_amdgcn_mfma_f32_16x16x16f16(a, b, c, 0, 0, 0);
}

__global__ __launch_bounds__(256, 4) void main_kernel(
    const float* __restrict__ t, const float2* __restrict__ pos,
    const float* __restrict__ poi_t, const int* __restrict__ batch,
    const float4* __restrict__ pg, const uint2* __restrict__ Wf,
    const float* __restrict__ Bf, float* __restrict__ out) {
  const int tid = threadIdx.x;
  const int lane = tid & 63;
  const int col = lane & 15;
  const int koct = lane >> 4;

  // ---- Phase 0: issue ALL streaming loads for 4 iterations upfront ----
  int base = blockIdx.x * 1024 + tid;
  int bi[4];
  float tvv[4];
  float2 pv[4];
#pragma unroll
  for (int r = 0; r < 4; ++r) {
    bi[r] = batch[base + r * 256];
    tvv[r] = t[base + r * 256];
    pv[r] = pos[base + r * 256];
  }
  // Gathers (2 per iter, depend only on bi[r]).
  float4 pgr[4];
  float ptg[4];
#pragma unroll
  for (int r = 0; r < 4; ++r) {
    pgr[r] = pg[bi[r]];
    ptg[r] = poi_t[bi[r]];
  }

  // Weight A-fragments + bias C-fragments (amortized over 4 iterations).
  half4 wa[7];
#pragma unroll
  for (int k = 0; k < 7; ++k)
    wa[k] = __builtin_bit_cast(half4, Wf[k * 64 + lane]);
  floatx4 cb[5];
#pragma unroll
  for (int s = 0; s < 5; ++s)
    cb[s] = *(const floatx4*)&Bf[s * 16 + koct * 4];
  floatx4 cz{0.f, 0.f, 0.f, 0.f};

  // ---- Phase 1: 4 iterations of 64-node wave MLP + reduce ----
#pragma unroll
  for (int r = 0; r < 4; ++r) {
    float f0 = tvv[r] - ptg[r];
    float dpx = pv[r].x - pgr[r].x, dpy = pv[r].y - pgr[r].y;
    float f1 = dpx * dpx + dpy * dpy;
    float inv_r = rsqrtf(f1);
    float f2 = (dpx * pgr[r].z + dpy * pgr[r].w) * inv_r;

    int fx = (int)pk_u32(f0, f1);
    int fy = (int)pk_u32(f2, 1.0f);  // 1.0 multiplies folded L1 bias

    half4 b1[4];
#pragma unroll
    for (int g = 0; g < 4; ++g) {
      int src = g * 16 + col;
      uint2 fr;
      fr.x = (uint)__shfl(fx, src);
      fr.y = (uint)__shfl(fy, src);
      b1[g] = __builtin_bit_cast(half4, fr);
    }

    // Layer-major: 4 independent group-chains per layer.
    floatx4 d[4];
    half4 a[4];
#pragma unroll
    for (int g = 0; g < 4; ++g) d[g] = mfma16(wa[0], b1[g], cz);   // L1
#pragma unroll
    for (int g = 0; g < 4; ++g) a[g] = relu_cvt(d[g]);

    floatx4 d2a[4], d2b[4];
#pragma unroll
    for (int g = 0; g < 4; ++g) d2a[g] = mfma16(wa[1], a[g], cb[0]);
#pragma unroll
    for (int g = 0; g < 4; ++g) d2b[g] = mfma16(wa[2], a[g], cb[1]);
    half4 a3a[4], a3b[4];
#pragma unroll
    for (int g = 0; g < 4; ++g) a3a[g] = relu_cvt(d2a[g]);
#pragma unroll
    for (int g = 0; g < 4; ++g) a3b[g] = relu_cvt(d2b[g]);

#pragma unroll
    for (int g = 0; g < 4; ++g) d[g] = mfma16(wa[3], a3a[g], cb[2]);
#pragma unroll
    for (int g = 0; g < 4; ++g) d[g] = mfma16(wa[4], a3b[g], d[g]);
#pragma unroll
    for (int g = 0; g < 4; ++g) a[g] = relu_cvt(d[g]);

#pragma unroll
    for (int g = 0; g < 4; ++g) d[g] = mfma16(wa[5], a[g], cb[3]);
#pragma unroll
    for (int g = 0; g < 4; ++g) a[g] = relu_cvt(d[g]);

#pragma unroll
    for (int g = 0; g < 4; ++g) d[g] = mfma16(wa[6], a[g], cb[4]);

    float wg0 = __shfl(d[0][0], col);
    float wg1 = __shfl(d[1][0], col);
    float wg2 = __shfl(d[2][0], col);
    float wg3 = __shfl(d[3][0], col);
    float w = wg0;
    w = (koct == 1) ? wg1 : w;
    w = (koct == 2) ? wg2 : w;
    w = (koct == 3) ? wg3 : w;

    float invn = (f1 > 0.f) ? inv_r : 0.f;
    seg_atomic_add2(bi[r], w * dpx * invn, w * dpy * invn, out);
  }
}

extern "C" void kernel_launch(void* const* d_in, const int* in_sizes, int n_in,
                              void* d_out, int out_size, void* d_ws,
                              size_t ws_size, hipStream_t stream) {
  const float* t = (const float*)d_in[0];
  const float2* pos = (const float2*)d_in[1];
  const float* poi_t = (const float*)d_in[2];
  const float2* poi_pos = (const float2*)d_in[3];
  const int* batch = (const int*)d_in[4];
  const float* W1 = (const float*)d_in[5];
  const float* B1 = (const float*)d_in[6];
  const float* W2 = (const float*)d_in[7];
  const float* B2 = (const float*)d_in[8];
  const float* W3 = (const float*)d_in[9];
  const float* B3 = (const float*)d_in[10];
  const float* W4 = (const float*)d_in[11];
  const float* B4 = (const float*)d_in[12];
  const float* W5 = (const float*)d_in[13];
  const float* B5 = (const float*)d_in[14];
  float* out = (float*)d_out;

  float* csum = (float*)d_ws;                  // [NB*2]
  float4* pg = (float4*)(csum + 2 * NB);       // [NB]
  uint2* Wf = (uint2*)(pg + NB);               // [448]
  float* Bf = (float*)(Wf + 448);              // [80]

  hipMemsetAsync(csum, 0, 2 * NB * sizeof(float), stream);
  hipMemsetAsync(d_out, 0, 2 * NB * sizeof(float), stream);

  prepack_kernel<<<3, 256, 0, stream>>>(W1, W2, W3, W4, W5, B1, B2, B3, B4,
                                        B5, Wf, Bf);
  centroid_kernel<<<NN / 1024, 256, 0, stream>>>(pos, batch, csum);
  graphvec_kernel<<<NB / 256, 256, 0, stream>>>(csum, poi_pos, pg);
  main_kernel<<<NN / 1024, 256, 0, stream>>>(t, pos, poi_t, batch, pg, Wf,
                                             Bf, out);
}

// Round 12
// 50.842 us; speedup vs baseline: 1.3964x; 1.1498x over previous
//
#include <hip/hip_runtime.h>

#define NN 4194304
#define NB 16384

typedef _Float16 half4 __attribute__((ext_vector_type(4)));
typedef float floatx4 __attribute__((ext_vector_type(4)));
typedef unsigned int uint;

__device__ __forceinline__ uint pk_u32(float lo, float hi) {
  return __builtin_bit_cast(uint, __builtin_amdgcn_cvt_pkrtz(lo, hi));
}

__device__ __forceinline__ half4 relu_cvt(floatx4 d) {
  uint2 u;
  u.x = pk_u32(d[0], d[1]);
  u.y = pk_u32(d[2], d[3]);
  half4 h = __builtin_bit_cast(half4, u);
  return __builtin_elementwise_max(h, half4{0, 0, 0, 0});
}

// DPP butterfly wave64 sum; total lands in lane 63. 6 VALU adds, no LDS.
template <int CTRL>
__device__ __forceinline__ float dpp_add(float x) {
  int y = __builtin_amdgcn_update_dpp(0, __builtin_bit_cast(int, x), CTRL,
                                      0xf, 0xf, true);
  return x + __builtin_bit_cast(float, y);
}
__device__ __forceinline__ float wave_sum(float x) {
  x = dpp_add<0x111>(x);
  x = dpp_add<0x112>(x);
  x = dpp_add<0x114>(x);
  x = dpp_add<0x118>(x);
  x = dpp_add<0x142>(x);
  x = dpp_add<0x143>(x);
  return x;
}

// Segmented reduce + atomics. Fast path: wave-uniform segment (avg run = 256).
__device__ __forceinline__ void seg_atomic_add2(int b, float vx, float vy,
                                                float* __restrict__ out) {
  const int lane = threadIdx.x & 63;
  int b0 = __builtin_amdgcn_readfirstlane(b);
  if (__ballot(b == b0) == ~0ull) {
    float sx = wave_sum(vx);
    float sy = wave_sum(vy);
    if (lane == 63) {
      atomicAdd(&out[2 * b0], sx);
      atomicAdd(&out[2 * b0 + 1], sy);
    }
    return;
  }
  int bprev = __shfl_up(b, 1);
  bool head = (lane == 0) || (b != bprev);
  unsigned long long hb = __ballot(head);
  unsigned long long mask_le = hb << (63 - lane);
  int run_start = lane - __clzll(mask_le);
  float sx = vx, sy = vy;
#pragma unroll
  for (int off = 1; off < 64; off <<= 1) {
    float ox = __shfl_up(sx, off);
    float oy = __shfl_up(sy, off);
    if (lane - off >= run_start) { sx += ox; sy += oy; }
  }
  int bnext = __shfl_down(b, 1);
  bool tail = (lane == 63) || (b != bnext);
  if (tail) {
    atomicAdd(&out[2 * b], sx);
    atomicAdd(&out[2 * b + 1], sy);
  }
}

// 4 nodes/thread: loads hoisted, stalls amortized.
__global__ __launch_bounds__(256) void centroid_kernel(
    const float2* __restrict__ pos, const int* __restrict__ batch,
    float* __restrict__ csum) {
  int base = blockIdx.x * 1024 + threadIdx.x;
  int bi[4];
  float2 pv[4];
#pragma unroll
  for (int r = 0; r < 4; ++r) {
    bi[r] = batch[base + r * 256];
    pv[r] = pos[base + r * 256];
  }
#pragma unroll
  for (int r = 0; r < 4; ++r) seg_atomic_add2(bi[r], pv[r].x, pv[r].y, csum);
}

// Per-graph packed record: {poi_pos.x, poi_pos.y, udc.x, udc.y}
__global__ __launch_bounds__(256) void graphvec_kernel(
    const float* __restrict__ csum, const float2* __restrict__ poi_pos,
    float4* __restrict__ pg) {
  int i = blockIdx.x * 256 + threadIdx.x;
  float2 pp = poi_pos[i];
  float dcx = csum[2 * i] - pp.x;
  float dcy = csum[2 * i + 1] - pp.y;
  float inv = rsqrtf(dcx * dcx + dcy * dcy);
  pg[i] = float4{pp.x, pp.y, dcx * inv, dcy * inv};
}

// Prepack weights into A-fragments of mfma_f32_16x16x16f16 (W as A: M=out,K=in).
// ALL biases folded via fake constant-1 neurons:
//   tile0: W1 (10x3); k=3: B1 col; row10 = bias-1 neuron
//   tile1: W2 rows 0-15 (K=10); k=10: B2[row] (input = L1 fake = 1)
//   tile2: W2 rows 16-19;       k=10: B2[16+row]; row4 = bias-1 neuron (h2[20]=1)
//   tile3: W3 k0-15
//   tile4: W3 k16-19; local k=4 (=k20, input h2[20]=1): B3[row]; row10 = bias-1
//   tile5: W4 (5x10); k=10 (input h3[10]=1): B4[row]; row5 = bias-1
//   tile6: W5 (1x5);  k=5 (input h4[5]=1): B5[0]
// Blocks 3..66 zero csum (8192 float4) and out (8192 float4).
__global__ void prepack_kernel(
    const float* __restrict__ W1, const float* __restrict__ W2,
    const float* __restrict__ W3, const float* __restrict__ W4,
    const float* __restrict__ W5, const float* __restrict__ B1,
    const float* __restrict__ B2, const float* __restrict__ B3,
    const float* __restrict__ B4, const float* __restrict__ B5,
    uint2* __restrict__ Wf, float* __restrict__ csum,
    float* __restrict__ out) {
  if (blockIdx.x >= 3) {
    int z = (blockIdx.x - 3) * 256 + threadIdx.x;  // 0..16383
    float4 zero{0.f, 0.f, 0.f, 0.f};
    if (z < 8192) ((float4*)csum)[z] = zero;
    else ((float4*)out)[z - 8192] = zero;
    return;
  }
  int p = blockIdx.x * 256 + threadIdx.x;
  if (p >= 448) return;
  int tile = p >> 6, lane = p & 63, row = lane & 15, kb = (lane >> 4) * 4;
  float v[4];
#pragma unroll
  for (int i = 0; i < 4; ++i) {
    int k = kb + i;
    float x = 0.f;
    switch (tile) {
      case 0:
        if (row < 10 && k < 3) x = W1[row * 3 + k];
        if (k == 3) { if (row < 10) x = B1[row]; else if (row == 10) x = 1.f; }
        break;
      case 1:
        if (k < 10) x = W2[row * 10 + k];
        else if (k == 10) x = B2[row];
        break;
      case 2:
        if (row < 4 && k < 10) x = W2[(16 + row) * 10 + k];
        if (k == 10) { if (row < 4) x = B2[16 + row]; else if (row == 4) x = 1.f; }
        break;
      case 3:
        if (row < 10 && k < 16) x = W3[row * 20 + k];
        break;
      case 4:
        if (row < 10 && k < 4) x = W3[row * 20 + 16 + k];
        if (k == 4) { if (row < 10) x = B3[row]; else if (row == 10) x = 1.f; }
        break;
      case 5:
        if (row < 5 && k < 10) x = W4[row * 10 + k];
        if (k == 10) { if (row < 5) x = B4[row]; else if (row == 5) x = 1.f; }
        break;
      default:
        if (row == 0 && k < 5) x = W5[k];
        if (row == 0 && k == 5) x = B5[0];
        break;
    }
    v[i] = x;
  }
  Wf[p] = uint2{pk_u32(v[0], v[1]), pk_u32(v[2], v[3])};
}

__device__ __forceinline__ floatx4 mfma16(half4 a, half4 b, floatx4 c) {
  return __builtin_amdgcn_mfma_f32_16x16x16f16(a, b, c, 0, 0, 0);
}

__global__ __launch_bounds__(256, 3) void main_kernel(
    const float* __restrict__ t, const float2* __restrict__ pos,
    const float* __restrict__ poi_t, const int* __restrict__ batch,
    const float4* __restrict__ pg, const uint2* __restrict__ Wf,
    float* __restrict__ out) {
  const int tid = threadIdx.x;
  const int lane = tid & 63;
  const int col = lane & 15;
  const int koct = lane >> 4;

  // ---- Phase 0: all streaming loads + gathers for 4 iterations upfront ----
  int base = blockIdx.x * 1024 + tid;
  int bi[4];
  float tvv[4];
  float2 pv[4];
#pragma unroll
  for (int r = 0; r < 4; ++r) {
    bi[r] = batch[base + r * 256];
    tvv[r] = t[base + r * 256];
    pv[r] = pos[base + r * 256];
  }
  float4 pgr[4];
  float ptg[4];
#pragma unroll
  for (int r = 0; r < 4; ++r) {
    pgr[r] = pg[bi[r]];
    ptg[r] = poi_t[bi[r]];
  }

  // Weight A-fragments (all biases folded -> no C fragments).
  half4 wa[7];
#pragma unroll
  for (int k = 0; k < 7; ++k)
    wa[k] = __builtin_bit_cast(half4, Wf[k * 64 + lane]);
  floatx4 cz{0.f, 0.f, 0.f, 0.f};

  // ---- Phase 1: 2 passes x 2 iterations -> 8 MFMA chains per layer ----
#pragma unroll
  for (int rp = 0; rp < 2; ++rp) {
    float dpx[2], dpy[2], f1v[2], invr[2];
    int fx[2], fy[2];
#pragma unroll
    for (int u = 0; u < 2; ++u) {
      int r = rp * 2 + u;
      float f0 = tvv[r] - ptg[r];
      dpx[u] = pv[r].x - pgr[r].x;
      dpy[u] = pv[r].y - pgr[r].y;
      f1v[u] = dpx[u] * dpx[u] + dpy[u] * dpy[u];
      invr[u] = rsqrtf(f1v[u]);
      float f2 = (dpx[u] * pgr[r].z + dpy[u] * pgr[r].w) * invr[u];
      fx[u] = (int)pk_u32(f0, f1v[u]);
      fy[u] = (int)pk_u32(f2, 1.0f);  // 1.0 feeds the folded-bias column
    }

    half4 b1[8];
#pragma unroll
    for (int u = 0; u < 2; ++u)
#pragma unroll
      for (int g = 0; g < 4; ++g) {
        int src = g * 16 + col;
        uint2 fr;
        fr.x = (uint)__shfl(fx[u], src);
        fr.y = (uint)__shfl(fy[u], src);
        b1[u * 4 + g] = __builtin_bit_cast(half4, fr);
      }

    floatx4 d[8];
    half4 a[8];
#pragma unroll
    for (int c = 0; c < 8; ++c) d[c] = mfma16(wa[0], b1[c], cz);  // L1
#pragma unroll
    for (int c = 0; c < 8; ++c) a[c] = relu_cvt(d[c]);

    floatx4 d2[8];
    half4 a3a[8], a3b[8];
#pragma unroll
    for (int c = 0; c < 8; ++c) d2[c] = mfma16(wa[1], a[c], cz);  // L2 M0-15
#pragma unroll
    for (int c = 0; c < 8; ++c) a3a[c] = relu_cvt(d2[c]);
#pragma unroll
    for (int c = 0; c < 8; ++c) d2[c] = mfma16(wa[2], a[c], cz);  // L2 M16-20
#pragma unroll
    for (int c = 0; c < 8; ++c) a3b[c] = relu_cvt(d2[c]);

#pragma unroll
    for (int c = 0; c < 8; ++c) d[c] = mfma16(wa[3], a3a[c], cz); // L3 k0-15
#pragma unroll
    for (int c = 0; c < 8; ++c) d[c] = mfma16(wa[4], a3b[c], d[c]); // L3 k16+
#pragma unroll
    for (int c = 0; c < 8; ++c) a[c] = relu_cvt(d[c]);

#pragma unroll
    for (int c = 0; c < 8; ++c) d[c] = mfma16(wa[5], a[c], cz);   // L4
#pragma unroll
    for (int c = 0; c < 8; ++c) a[c] = relu_cvt(d[c]);

#pragma unroll
    for (int c = 0; c < 8; ++c) d[c] = mfma16(wa[6], a[c], cz);   // L5

#pragma unroll
    for (int u = 0; u < 2; ++u) {
      float wg0 = __shfl(d[u * 4 + 0][0], col);
      float wg1 = __shfl(d[u * 4 + 1][0], col);
      float wg2 = __shfl(d[u * 4 + 2][0], col);
      float wg3 = __shfl(d[u * 4 + 3][0], col);
      float w = wg0;
      w = (koct == 1) ? wg1 : w;
      w = (koct == 2) ? wg2 : w;
      w = (koct == 3) ? wg3 : w;
      float invn = (f1v[u] > 0.f) ? invr[u] : 0.f;
      seg_atomic_add2(bi[rp * 2 + u], w * dpx[u] * invn, w * dpy[u] * invn,
                      out);
    }
  }
}

extern "C" void kernel_launch(void* const* d_in, const int* in_sizes, int n_in,
                              void* d_out, int out_size, void* d_ws,
                              size_t ws_size, hipStream_t stream) {
  const float* t = (const float*)d_in[0];
  const float2* pos = (const float2*)d_in[1];
  const float* poi_t = (const float*)d_in[2];
  const float2* poi_pos = (const float2*)d_in[3];
  const int* batch = (const int*)d_in[4];
  const float* W1 = (const float*)d_in[5];
  const float* B1 = (const float*)d_in[6];
  const float* W2 = (const float*)d_in[7];
  const float* B2 = (const float*)d_in[8];
  const float* W3 = (const float*)d_in[9];
  const float* B3 = (const float*)d_in[10];
  const float* W4 = (const float*)d_in[11];
  const float* B4 = (const float*)d_in[12];
  const float* W5 = (const float*)d_in[13];
  const float* B5 = (const float*)d_in[14];
  float* out = (float*)d_out;

  float* csum = (float*)d_ws;                  // [NB*2]
  float4* pg = (float4*)(csum + 2 * NB);       // [NB]
  uint2* Wf = (uint2*)(pg + NB);               // [448]

  // prepack blocks 0-2 pack weights; blocks 3-66 zero csum + out.
  prepack_kernel<<<67, 256, 0, stream>>>(W1, W2, W3, W4, W5, B1, B2, B3, B4,
                                         B5, Wf, csum, out);
  centroid_kernel<<<NN / 1024, 256, 0, stream>>>(pos, batch, csum);
  graphvec_kernel<<<NB / 256, 256, 0, stream>>>(csum, poi_pos, pg);
  main_kernel<<<NN / 1024, 256, 0, stream>>>(t, pos, poi_t, batch, pg, Wf,
                                             out);
}